// Round 3
// baseline (1338.420 us; speedup 1.0000x reference)
//
#include <hip/hip_runtime.h>
#include <math.h>

// Router: logits = X[32768,2048] @ W[64,2048]^T ; softmax over 64; top-8 (stable).
// 512 blocks x 4 waves. Block owns 64 rows; wave owns a 512-wide k-slice.
// Main loop per wave (no barriers): stage X[64 rows][64 k] to wave-private LDS via
// global_load_lds width=16 (coalesced), then 8x8 register outer product per thread
// (rows r0+8i, experts e0+8j). x from LDS b128 (k-phase rotated, 2-way banks only),
// w from global float4 broadcast (L2-resident 512 KB). Chunk-16 partial sums keep
// accumulation error ~1e-7 so top-8 indices match the numpy fp32 reference.

constexpr int HD   = 2048;
constexpr int NE   = 64;
constexpr int RPB  = 64;    // rows per block
constexpr int TOPK = 8;
constexpr int KSL  = 512;   // k-slice per wave
constexpr int BK   = 64;    // k-tile staged per iteration
constexpr int NIT  = KSL / BK;  // 8

typedef void __attribute__((address_space(1)))* gas_t;
typedef void __attribute__((address_space(3)))* las_t;

__device__ __forceinline__ void gload_lds16(const float* g, float* l) {
  // LDS dest is wave-uniform base + lane*16 (m104); pass the uniform base.
  __builtin_amdgcn_global_load_lds((gas_t)(uintptr_t)g, (las_t)l, 16, 0, 0);
}

__global__ __launch_bounds__(256, 2)
void router_k(const float* __restrict__ X, const float* __restrict__ W,
              float* __restrict__ probs, float* __restrict__ topv,
              float* __restrict__ topi) {
  // x tiles: 4 waves x 64 rows x 64 floats = 64 KB (unpadded: global_load_lds
  // requires linear lane order). Epilogue red[2][64][72] (36,864 B) aliases it.
  __shared__ float lds[4 * RPB * BK];

  const int tid  = threadIdx.x;
  const int wv   = tid >> 6;
  const int lane = tid & 63;
  const int r0   = lane >> 3;   // row sub-index (8 rows: r0+8i)
  const int e0   = lane & 7;    // expert sub-index (8 experts: e0+8j)
  const int rowbase = blockIdx.x * RPB;

  float* xt = lds + wv * (RPB * BK);          // wave-private tile
  // staging source: lane covers row (lane>>4), col (lane&15)*4 within a 4-row strip
  const float* gx = X + (size_t)(rowbase + (lane >> 4)) * HD + wv * KSL + (lane & 15) * 4;
  const float* wb = W + (size_t)e0 * HD + wv * KSL;

  float acc[8][8];
#pragma unroll
  for (int i = 0; i < 8; ++i)
#pragma unroll
    for (int j = 0; j < 8; ++j) acc[i][j] = 0.f;

  for (int it = 0; it < NIT; ++it) {
    // all prior ds_read results consumed; make sure nothing is in flight before
    // overwriting the tile, and keep the compiler from reordering across.
    asm volatile("s_waitcnt lgkmcnt(0)" ::: "memory");
#pragma unroll
    for (int i = 0; i < 16; ++i)
      gload_lds16(gx + (size_t)i * 4 * HD + it * BK, xt + i * 256);
    asm volatile("s_waitcnt vmcnt(0)" ::: "memory");

#pragma unroll
    for (int cg = 0; cg < 4; ++cg) {          // 16-k chunks (precision chunking)
      float ps[8][8];
#pragma unroll
      for (int q = 0; q < 4; ++q) {
        const int phi = (q + r0) & 3;         // k-phase rotation: 2-way banks only
        const int kk  = cg * 16 + phi * 4;
        float4 xq[8], wq[8];
#pragma unroll
        for (int i = 0; i < 8; ++i)
          xq[i] = *reinterpret_cast<const float4*>(xt + (r0 + 8 * i) * BK + kk);
#pragma unroll
        for (int j = 0; j < 8; ++j)
          wq[j] = *reinterpret_cast<const float4*>(wb + (size_t)j * 8 * HD + it * BK + kk);
#pragma unroll
        for (int i = 0; i < 8; ++i)
#pragma unroll
          for (int j = 0; j < 8; ++j) {
            float t = (q == 0) ? (xq[i].x * wq[j].x)
                               : fmaf(xq[i].x, wq[j].x, ps[i][j]);
            t = fmaf(xq[i].y, wq[j].y, t);
            t = fmaf(xq[i].z, wq[j].z, t);
            t = fmaf(xq[i].w, wq[j].w, t);
            ps[i][j] = t;
          }
      }
#pragma unroll
      for (int i = 0; i < 8; ++i)
#pragma unroll
        for (int j = 0; j < 8; ++j) acc[i][j] += ps[i][j];
    }
  }

  // ---- cross-wave (k-split) tree reduction: (w0+w2) + (w1+w3) ----
  // red stride 72: bank = (8*r0 + e0) % 32 -> 2-way (free), vs 65's 8-way.
  float (*red)[RPB][72] = reinterpret_cast<float (*)[RPB][72]>(lds);
  __syncthreads();   // everyone done with x tiles before aliasing
  if (wv >= 2) {
#pragma unroll
    for (int i = 0; i < 8; ++i)
#pragma unroll
      for (int j = 0; j < 8; ++j)
        red[wv - 2][r0 + 8 * i][e0 + 8 * j] = acc[i][j];
  }
  __syncthreads();
  if (wv < 2) {
#pragma unroll
    for (int i = 0; i < 8; ++i)
#pragma unroll
      for (int j = 0; j < 8; ++j)
        acc[i][j] += red[wv][r0 + 8 * i][e0 + 8 * j];
  }
  __syncthreads();
  if (wv == 1) {
#pragma unroll
    for (int i = 0; i < 8; ++i)
#pragma unroll
      for (int j = 0; j < 8; ++j)
        red[0][r0 + 8 * i][e0 + 8 * j] = acc[i][j];
  }
  __syncthreads();
  if (wv == 0) {
#pragma unroll
    for (int i = 0; i < 8; ++i)
#pragma unroll
      for (int j = 0; j < 8; ++j)
        red[1][r0 + 8 * i][e0 + 8 * j] = acc[i][j] + red[0][r0 + 8 * i][e0 + 8 * j];
  }
  __syncthreads();

  // ---- epilogue: softmax + stable top-8; 16 rows per wave, lane == expert ----
  for (int k = 0; k < RPB / 4; ++k) {
    const int rr = wv * (RPB / 4) + k;
    const float lg = red[1][rr][lane];

    float m = lg;
#pragma unroll
    for (int off = 32; off; off >>= 1)
      m = fmaxf(m, __shfl_xor(m, off, 64));

    const float ex = expf(lg - m);
    float s = ex;
#pragma unroll
    for (int off = 32; off; off >>= 1)
      s += __shfl_xor(s, off, 64);

    const float p = ex * (1.0f / s);
    probs[(size_t)(rowbase + rr) * NE + lane] = p;

    // stable rank: #(p_j > p) + #(p_j == p with j < lane) -> matches lax.top_k ties
    int rank = 0;
#pragma unroll
    for (int j = 0; j < NE; ++j) {
      const float pj = __shfl(p, j, 64);
      rank += (pj > p) || (pj == p && j < lane);
    }
    if (rank < TOPK) {
      topv[(size_t)(rowbase + rr) * TOPK + rank] = p;
      topi[(size_t)(rowbase + rr) * TOPK + rank] = (float)lane;
    }
  }
}

extern "C" void kernel_launch(void* const* d_in, const int* in_sizes, int n_in,
                              void* d_out, int out_size, void* d_ws, size_t ws_size,
                              hipStream_t stream) {
  const float* X = (const float*)d_in[0];
  const float* W = (const float*)d_in[1];
  const int n = in_sizes[0] / HD;          // 32768 tokens

  float* probs = (float*)d_out;
  float* topv  = probs + (size_t)n * NE;
  float* topi  = topv + (size_t)n * TOPK;

  dim3 grid(n / RPB), block(256);
  hipLaunchKernelGGL(router_k, grid, block, 0, stream, X, W, probs, topv, topi);
}

// Round 4
// 422.782 us; speedup vs baseline: 3.1657x; 3.1657x over previous
//
#include <hip/hip_runtime.h>
#include <math.h>

// Router: logits = X[32768,2048] @ W[64,2048]^T ; softmax over 64; top-8 (stable).
// MFMA fp16 2-split path: x = xh+xl, w = wh+wl (exact fp32 splits, inputs scaled
// by 2^12/2^13 to avoid f16 denormals); logit = [xh*wh] + [xh*wl + xl*wh], the
// bracketed sums in separate fp32 MFMA accumulators (cross-acc is ~2^-12 smaller,
// so its fold rounding is negligible). Residual ~2e-7 on logits = same class as
// the chunked-fp32 kernels that passed rounds 1-3. Descale by exact 2^-25.
//
// Block = 256 thr / 4 waves, 64 rows. Waves split M (16 rows each, full K): no
// cross-wave reduction. K streamed in BK=64 tiles, m97-style double buffer:
//  - X tile (16 KB fp32) via global_load_lds, XOR-swizzled at 16B-granule level
//    (granule(row,kq) = row*16 + (kq ^ (row&15))) -> coalesced stores AND
//    conflict-free (<=2-way) ds_read_b128 A-fragment reads.
//  - W tile converted once/block/tile to f16 hi/lo in LDS (granule e*8+(kg^(e&7))).
// MFMA: v_mfma_f32_16x16x32_f16, A[m=lane&15][k=(lane>>4)*8+j] from X rows,
// B[n=lane&15][k] from W rows (B^T form, m91-verified), C row=(lane>>4)*4+r, col=lane&15.

constexpr int HD = 2048, NE = 64, RPB = 64, BK = 64, NT = HD / BK, TOPK = 8;
constexpr float XSC = 4096.f;     // 2^12
constexpr float WSC = 8192.f;     // 2^13
constexpr float DESCALE = 1.0f / (XSC * WSC);   // exact 2^-25

typedef _Float16 f16x8 __attribute__((ext_vector_type(8)));
typedef float f32x4 __attribute__((ext_vector_type(4)));
typedef void __attribute__((address_space(1)))* gas_t;
typedef void __attribute__((address_space(3)))* las_t;

__device__ __forceinline__ void gload_lds16(const float* g, void* l) {
  __builtin_amdgcn_global_load_lds((gas_t)(uintptr_t)g, (las_t)l, 16, 0, 0);
}

__global__ __launch_bounds__(256, 2)
void router_k(const float* __restrict__ X, const float* __restrict__ W,
              float* __restrict__ probs, float* __restrict__ topv,
              float* __restrict__ topi) {
  __shared__ float4 smem4[4096];            // 65536 B
  char* smem = (char*)smem4;
  // xbuf[2] @ 0 (2*16384 B) ; wbuf[2] @ 32768 (per buf: hi 8192 B + lo 8192 B)

  const int tid = threadIdx.x, wv = tid >> 6, lane = tid & 63;
  const int m_l = lane & 15, q_l = lane >> 4;
  const int rowbase = blockIdx.x * RPB;

  // gll staging: wave wv executes instrs i = 4m+wv; lane covers row 16m+4wv+q_l,
  // granule kq = m_l ^ ((4wv+q_l)&15)  (XOR-swizzle, consistent with reads below)
  const int kq_st = m_l ^ ((4 * wv + q_l) & 15);
  const float* gx = X + (size_t)(rowbase + 4 * wv + q_l) * HD + kq_st * 4;

  // W staging: thread -> expert we = tid>>2, 16k-quarter wq = tid&3
  const int we = tid >> 2, wq = tid & 3;
  const float* gw = W + (size_t)we * HD + wq * 16;
  const int g0 = we * 8 + ((2 * wq) ^ (we & 7));
  const int g1 = we * 8 + ((2 * wq + 1) ^ (we & 7));

  // prologue: X tile 0 in flight, W tile 0 in regs
#pragma unroll
  for (int m = 0; m < 4; ++m)
    gload_lds16(gx + (size_t)m * 16 * HD, smem + (4 * m + wv) * 1024);
  float4 wr[4];
#pragma unroll
  for (int j = 0; j < 4; ++j) wr[j] = *(const float4*)(gw + j * 4);

  f32x4 acc_hh[4], acc_cr[4];
#pragma unroll
  for (int nt = 0; nt < 4; ++nt) {
    acc_hh[nt] = {0.f, 0.f, 0.f, 0.f};
    acc_cr[nt] = {0.f, 0.f, 0.f, 0.f};
  }

  for (int t = 0; t < NT; ++t) {
    const int cur = t & 1;
    char* xcur = smem + cur * 16384;
    char* wcur = smem + 32768 + cur * 16384;

    { // stage W(t): fp32 regs -> f16 hi/lo in wbuf[cur]
      float v[16];
#pragma unroll
      for (int j = 0; j < 4; ++j) {
        v[4 * j] = wr[j].x; v[4 * j + 1] = wr[j].y;
        v[4 * j + 2] = wr[j].z; v[4 * j + 3] = wr[j].w;
      }
      f16x8 h0, h1, l0, l1;
#pragma unroll
      for (int j = 0; j < 8; ++j) {
        float a = v[j] * WSC;     _Float16 ha = (_Float16)a;
        h0[j] = ha; l0[j] = (_Float16)(a - (float)ha);
        float b = v[j + 8] * WSC; _Float16 hb = (_Float16)b;
        h1[j] = hb; l1[j] = (_Float16)(b - (float)hb);
      }
      *(f16x8*)(wcur + g0 * 16) = h0;
      *(f16x8*)(wcur + g1 * 16) = h1;
      *(f16x8*)(wcur + 8192 + g0 * 16) = l0;
      *(f16x8*)(wcur + 8192 + g1 * 16) = l1;
    }
    if (t + 1 < NT) {          // prefetch W(t+1) into regs
#pragma unroll
      for (int j = 0; j < 4; ++j)
        wr[j] = *(const float4*)(gw + (t + 1) * BK + j * 4);
    }
    __syncthreads();           // drains gll(t) + W ds_writes; bufs[cur] ready
    if (t + 1 < NT) {          // async prefetch X(t+1), flies over compute(t)
      char* xnxt = smem + (1 - cur) * 16384;
#pragma unroll
      for (int m = 0; m < 4; ++m)
        gload_lds16(gx + (size_t)m * 16 * HD + (t + 1) * BK, xnxt + (4 * m + wv) * 1024);
    }

    // compute tile t: 2 K=32 steps, 4 N-tiles, 3 MFMAs each
#pragma unroll
    for (int s = 0; s < 2; ++s) {
      const int row_l = 16 * wv + m_l;          // this lane's A row
      const int kq0 = 8 * s + 2 * q_l;
      const int G0 = row_l * 16 + (kq0 ^ m_l);
      const int G1 = row_l * 16 + ((kq0 + 1) ^ m_l);
      f32x4 xa = *(const f32x4*)(xcur + G0 * 16);   // k +0..3
      f32x4 xb = *(const f32x4*)(xcur + G1 * 16);   // k +4..7
      f16x8 ah, al;
#pragma unroll
      for (int j = 0; j < 4; ++j) {
        float a = xa[j] * XSC; _Float16 ha = (_Float16)a;
        ah[j] = ha; al[j] = (_Float16)(a - (float)ha);
        float b = xb[j] * XSC; _Float16 hb = (_Float16)b;
        ah[j + 4] = hb; al[j + 4] = (_Float16)(b - (float)hb);
      }
      const int kgB = 4 * s + q_l;
#pragma unroll
      for (int nt = 0; nt < 4; ++nt) {
        const int ee = nt * 16 + m_l;
        const int gb = ee * 8 + (kgB ^ (ee & 7));
        f16x8 bh = *(const f16x8*)(wcur + gb * 16);
        f16x8 bl = *(const f16x8*)(wcur + 8192 + gb * 16);
        acc_hh[nt] = __builtin_amdgcn_mfma_f32_16x16x32_f16(ah, bh, acc_hh[nt], 0, 0, 0);
        acc_cr[nt] = __builtin_amdgcn_mfma_f32_16x16x32_f16(ah, bl, acc_cr[nt], 0, 0, 0);
        acc_cr[nt] = __builtin_amdgcn_mfma_f32_16x16x32_f16(al, bh, acc_cr[nt], 0, 0, 0);
      }
    }
  }

  __syncthreads();                      // everyone done with xbuf
  float* plds = (float*)smem;           // logits [64][68] fp32 (17.4 KB)
#pragma unroll
  for (int nt = 0; nt < 4; ++nt)
#pragma unroll
    for (int r = 0; r < 4; ++r)
      plds[(16 * wv + 4 * q_l + r) * 68 + nt * 16 + m_l] =
          (acc_hh[nt][r] + acc_cr[nt][r]) * DESCALE;
  __syncthreads();

  // per-row softmax + stable top-8; wave wv owns rows 16wv..16wv+15, lane==expert
  for (int rr = 0; rr < 16; ++rr) {
    const int row_l = wv * 16 + rr;
    const float lg = plds[row_l * 68 + lane];

    float mx = lg;
#pragma unroll
    for (int off = 32; off; off >>= 1)
      mx = fmaxf(mx, __shfl_xor(mx, off, 64));

    const float ex = expf(lg - mx);
    float sm = ex;
#pragma unroll
    for (int off = 32; off; off >>= 1)
      sm += __shfl_xor(sm, off, 64);

    const float p = ex * (1.0f / sm);
    probs[(size_t)(rowbase + row_l) * NE + lane] = p;

    // stable rank: #(p_j > p) + #(p_j == p with j < lane) -> matches lax.top_k
    int rank = 0;
#pragma unroll
    for (int j = 0; j < NE; ++j) {
      const float pj = __shfl(p, j, 64);
      rank += (pj > p) || (pj == p && j < lane);
    }
    if (rank < TOPK) {
      topv[(size_t)(rowbase + row_l) * TOPK + rank] = p;
      topi[(size_t)(rowbase + row_l) * TOPK + rank] = (float)lane;
    }
  }
}

extern "C" void kernel_launch(void* const* d_in, const int* in_sizes, int n_in,
                              void* d_out, int out_size, void* d_ws, size_t ws_size,
                              hipStream_t stream) {
  const float* X = (const float*)d_in[0];
  const float* W = (const float*)d_in[1];
  const int n = in_sizes[0] / HD;          // 32768 tokens

  float* probs = (float*)d_out;
  float* topv  = probs + (size_t)n * NE;
  float* topi  = topv + (size_t)n * TOPK;

  dim3 grid(n / RPB), block(256);
  hipLaunchKernelGGL(router_k, grid, block, 0, stream, X, W, probs, topv, topi);
}